// Round 1
// 954.875 us; speedup vs baseline: 1.0384x; 1.0384x over previous
//
#include <hip/hip_runtime.h>

// Attention fwd, fp32 I/O, bf16 MFMA internals.
// x[8,1024,1024] f32, w_qkv[1024,3072] f32, w_proj[1024,1024] f32, b_proj[1024] f32
// Outputs (concat in d_out, fp32): out[8,1024,1024] then attn[8,16,1024,1024]
// B=8, N=1024, C=1024, H=16, hd=64, scale=0.125

typedef unsigned short ushort_t;
typedef __bf16 bf16x8 __attribute__((ext_vector_type(8)));
typedef float floatx4 __attribute__((ext_vector_type(4)));

__device__ __forceinline__ ushort_t f2bf(float f) {
    __bf16 h = (__bf16)f;  // RNE
    return *(ushort_t*)&h;
}

// ---------------------------------------------------------------- transpose + cvt
// out[n][k] = (bf16) in[k][n]; in: rows x cols fp32, out: cols x rows bf16.
__global__ void transpose_f32_bf16(const float* __restrict__ in, ushort_t* __restrict__ out,
                                   int rows, int cols) {
    __shared__ ushort_t tile[32][33];
    int bx = blockIdx.x * 32;  // col base of input
    int by = blockIdx.y * 32;  // row base of input
    int tx = threadIdx.x;
    for (int i = threadIdx.y; i < 32; i += 8)
        tile[i][tx] = f2bf(in[(long)(by + i) * cols + bx + tx]);
    __syncthreads();
    for (int i = threadIdx.y; i < 32; i += 8)
        out[(long)(bx + i) * rows + by + tx] = tile[tx][i];
}

// ---------------------------------------------------------------- GEMM (Bt input)
// C[M][Nc] = A[M][K] @ Bt[Nc][K]^T, 128x128 tile, BK=32, 256 thr (4 waves, 2x2 of 64x64).
// AFP32: A is fp32 (converted to bf16 during staging); else A is bf16.
// MODE 0: scatter epilogue into q[B,H,N,64], k[B,H,N,64], vt[B,H,64,N] (bf16; qkv base = out_p)
// MODE 1: fp32 out_p[m][n] = acc + bias[n]
template <int AFP32>
__device__ __forceinline__ bf16x8 load_a8(const void* A_, long off) {
    if (AFP32) {
        const float* p = (const float*)A_ + off;
        floatx4 f0 = *(const floatx4*)p;
        floatx4 f1 = *(const floatx4*)(p + 4);
        bf16x8 r;
#pragma unroll
        for (int i = 0; i < 4; i++) { r[i] = (__bf16)f0[i]; r[i + 4] = (__bf16)f1[i]; }
        return r;
    } else {
        return *(const bf16x8*)((const ushort_t*)A_ + off);
    }
}

template <int MODE, int AFP32>
__global__ __launch_bounds__(256, 3)
void gemm_bt(const void* __restrict__ A, const ushort_t* __restrict__ Bt,
             int M, int Nc, int K,
             void* __restrict__ out_p, const float* __restrict__ bias) {
    __shared__ ushort_t As[128 * 32];
    __shared__ ushort_t Bs[128 * 32];
    const int tid  = threadIdx.x;
    const int wave = tid >> 6, lane = tid & 63;
    const int quad = lane >> 4, l16 = lane & 15;
    const int bm = blockIdx.y * 128, bn = blockIdx.x * 128;
    const int wm = (wave & 1) * 64, wn = (wave >> 1) * 64;

    floatx4 acc[4][4] = {};

    const int c0 = tid, c1 = tid + 256;
    const int row0 = c0 >> 2, kk0 = (c0 & 3) * 8;
    const int row1 = c1 >> 2, kk1 = (c1 & 3) * 8;

    for (int k0 = 0; k0 < K; k0 += 32) {
        bf16x8 a0 = load_a8<AFP32>(A, (long)(bm + row0) * K + k0 + kk0);
        bf16x8 a1 = load_a8<AFP32>(A, (long)(bm + row1) * K + k0 + kk1);
        bf16x8 b0 = *(const bf16x8*)(Bt + (long)(bn + row0) * K + k0 + kk0);
        bf16x8 b1 = *(const bf16x8*)(Bt + (long)(bn + row1) * K + k0 + kk1);
        __syncthreads();  // prev iteration fully consumed LDS
        *(bf16x8*)&As[c0 * 8] = a0;
        *(bf16x8*)&As[c1 * 8] = a1;
        *(bf16x8*)&Bs[c0 * 8] = b0;
        *(bf16x8*)&Bs[c1 * 8] = b1;
        __syncthreads();
        bf16x8 af[4], bfr[4];
#pragma unroll
        for (int i = 0; i < 4; i++) {
            af[i]  = *(const bf16x8*)&As[(wm + i * 16 + l16) * 32 + quad * 8];
            bfr[i] = *(const bf16x8*)&Bs[(wn + i * 16 + l16) * 32 + quad * 8];
        }
#pragma unroll
        for (int mi = 0; mi < 4; mi++)
#pragma unroll
            for (int ni = 0; ni < 4; ni++)
                acc[mi][ni] = __builtin_amdgcn_mfma_f32_16x16x32_bf16(af[mi], bfr[ni], acc[mi][ni], 0, 0, 0);
    }

    // epilogue. C/D layout: col = lane&15, row = quad*4 + reg (m89-verified)
    if (MODE == 0) {
        ushort_t* qb  = (ushort_t*)out_p;
        ushort_t* kb  = qb + (size_t)8388608;
        ushort_t* vtb = qb + (size_t)16777216;
#pragma unroll
        for (int ni = 0; ni < 4; ni++) {
            int n = bn + wn + ni * 16 + l16;
            int t = n >> 10, c = n & 1023, h = c >> 6, d = c & 63;
#pragma unroll
            for (int mi = 0; mi < 4; mi++) {
                floatx4 v = acc[mi][ni];
#pragma unroll
                for (int r = 0; r < 4; r++) {
                    int m = bm + wm + mi * 16 + quad * 4 + r;
                    int b = m >> 10, tok = m & 1023;
                    long bh = (long)b * 16 + h;
                    ushort_t val = f2bf(v[r]);
                    if (t == 0)      qb[(bh * 1024 + tok) * 64 + d] = val;
                    else if (t == 1) kb[(bh * 1024 + tok) * 64 + d] = val;
                    else             vtb[(bh * 64 + d) * 1024 + tok] = val;
                }
            }
        }
    } else {
        float* outf = (float*)out_p;
#pragma unroll
        for (int ni = 0; ni < 4; ni++) {
            int n = bn + wn + ni * 16 + l16;
            float bv = bias[n];
#pragma unroll
            for (int mi = 0; mi < 4; mi++) {
                floatx4 v = acc[mi][ni];
#pragma unroll
                for (int r = 0; r < 4; r++) {
                    int m = bm + wm + mi * 16 + quad * 4 + r;
                    outf[(long)m * Nc + n] = v[r] + bv;
                }
            }
        }
    }
}

// ---------------------------------------------------------------- fused attention
// grid: 8192 blocks = (bh in [0,128)) x (64 q-tiles of 16 rows); 256 threads (4 waves).
// S kept entirely in registers (floatx4 s[16] per thread = 4 rows x 16 keys).
// Softmax: in-reg trees + __shfl_xor(.,16) + tiny 4x16 LDS cross-wave exchange.
// P staged once to LDS as bf16, XOR-swizzled (byte ^= (row&7)<<4) for conflict-free
// ds_read_b128 A-fragments in the PV phase. LDS: 32KB+0.5KB -> 3-4 blocks/CU.
__global__ __launch_bounds__(256, 3)
void attn_fused(const ushort_t* __restrict__ q, const ushort_t* __restrict__ k,
                const ushort_t* __restrict__ vt, float* __restrict__ attn_out,
                ushort_t* __restrict__ ctx) {
    __shared__ ushort_t Sb[16 * 1024];   // bf16 P, row stride 2048B, XOR-swizzled
    __shared__ float redm[4][16];
    __shared__ float redl[4][16];

    const int bh = blockIdx.x >> 6;       // b*16 + h
    const int qt = blockIdx.x & 63;
    const int qbase = qt * 16;
    const int tid = threadIdx.x;
    const int wave = tid >> 6, lane = tid & 63;
    const int quad = lane >> 4, l16 = lane & 15;

    // ---- Phase 1: S = Q @ K^T (raw scores, scale folded into exp later).
    // Thread holds S[row=quad*4+r][key=key0+kt*16+l16] in s[kt][r].
    const ushort_t* qrow = q + ((long)bh * 1024 + qbase + l16) * 64 + quad * 8;
    bf16x8 aq0 = *(const bf16x8*)(qrow);
    bf16x8 aq1 = *(const bf16x8*)(qrow + 32);

    const int key0 = wave * 256;
    const ushort_t* kp = k + ((long)bh * 1024 + key0 + l16) * 64 + quad * 8;

    floatx4 s[16];
#pragma unroll
    for (int kt = 0; kt < 16; kt++) {
        const ushort_t* kpp = kp + (long)kt * 1024;  // 16 keys * 64
        bf16x8 bk0 = *(const bf16x8*)(kpp);
        bf16x8 bk1 = *(const bf16x8*)(kpp + 32);
        floatx4 s4 = {0.f, 0.f, 0.f, 0.f};
        s4 = __builtin_amdgcn_mfma_f32_16x16x32_bf16(aq0, bk0, s4, 0, 0, 0);
        s4 = __builtin_amdgcn_mfma_f32_16x16x32_bf16(aq1, bk1, s4, 0, 0, 0);
        s[kt] = s4;
    }

    // ---- Phase 2: softmax in registers.
    float m4[4], l4[4];
#pragma unroll
    for (int r = 0; r < 4; r++) {
        float m = s[0][r];
#pragma unroll
        for (int kt = 1; kt < 16; kt++) m = fmaxf(m, s[kt][r]);
#pragma unroll
        for (int o = 1; o < 16; o <<= 1) m = fmaxf(m, __shfl_xor(m, o, 16));
        m4[r] = m;
    }
    if (l16 == 0) {
#pragma unroll
        for (int r = 0; r < 4; r++) redm[wave][quad * 4 + r] = m4[r];
    }
    __syncthreads();
#pragma unroll
    for (int r = 0; r < 4; r++) {
        float m = redm[0][quad * 4 + r];
#pragma unroll
        for (int w = 1; w < 4; w++) m = fmaxf(m, redm[w][quad * 4 + r]);
        m4[r] = m;
        float l = 0.f;
#pragma unroll
        for (int kt = 0; kt < 16; kt++) {
            float p = __expf((s[kt][r] - m) * 0.125f);  // one exp pass, scale folded
            s[kt][r] = p;
            l += p;
        }
#pragma unroll
        for (int o = 1; o < 16; o <<= 1) l += __shfl_xor(l, o, 16);
        l4[r] = l;
    }
    if (l16 == 0) {
#pragma unroll
        for (int r = 0; r < 4; r++) redl[wave][quad * 4 + r] = l4[r];
    }
    __syncthreads();
#pragma unroll
    for (int r = 0; r < 4; r++) {
        float l = redl[0][quad * 4 + r] + redl[1][quad * 4 + r]
                + redl[2][quad * 4 + r] + redl[3][quad * 4 + r];
        l4[r] = 1.0f / l;
    }

    // ---- Phase 2b: write attn (fp32, direct from regs) + stage P bf16 to LDS.
    float* aout = attn_out + ((long)bh * 1024 + qbase) * 1024;
#pragma unroll
    for (int kt = 0; kt < 16; kt++) {
        int key = key0 + kt * 16 + l16;
#pragma unroll
        for (int r = 0; r < 4; r++) {
            int row = quad * 4 + r;
            float p = s[kt][r] * l4[r];
            aout[(long)row * 1024 + key] = p;
            int byt = row * 2048 + ((key * 2) ^ ((row & 7) << 4));
            *(ushort_t*)((char*)Sb + byt) = f2bf(p);
        }
    }
    __syncthreads();

    // ---- Phase 3: context = P @ V. wave w owns d-cols [w*16, w*16+16), K=1024 keys.
    // A-frag: P[row=l16][k = ks*32 + quad*8 + i], read swizzled as ds_read_b128.
    floatx4 o4 = {0.f, 0.f, 0.f, 0.f};
    const ushort_t* vrow = vt + ((long)bh * 64 + wave * 16 + l16) * 1024 + quad * 8;
    const char* sbrow = (const char*)Sb + l16 * 2048;
    const int sxor = (l16 & 7) << 4;
#pragma unroll 4
    for (int ks = 0; ks < 32; ks++) {
        bf16x8 pa = *(const bf16x8*)(sbrow + ((ks * 64 + quad * 16) ^ sxor));
        bf16x8 vb = *(const bf16x8*)(vrow + ks * 32);
        o4 = __builtin_amdgcn_mfma_f32_16x16x32_bf16(pa, vb, o4, 0, 0, 0);
    }
    // write ctx[B,N,C] bf16: row = qbase + quad*4 + r, col = h*64 + wave*16 + l16
    int b = bh >> 4, h = bh & 15;
    ushort_t* cp = ctx + ((long)b * 1024 + qbase) * 1024 + h * 64 + wave * 16 + l16;
#pragma unroll
    for (int r = 0; r < 4; r++)
        cp[(long)(quad * 4 + r) * 1024] = f2bf(o4[r]);
}

// ---------------------------------------------------------------- launch
extern "C" void kernel_launch(void* const* d_in, const int* in_sizes, int n_in,
                              void* d_out, int out_size, void* d_ws, size_t ws_size,
                              hipStream_t stream) {
    const float* x      = (const float*)d_in[0];
    const float* w_qkv  = (const float*)d_in[1];
    const float* w_proj = (const float*)d_in[2];
    const float* b_proj = (const float*)d_in[3];

    float* out  = (float*)d_out;                             // [8,1024,1024] fp32
    float* attn = out + (size_t)8 * 1024 * 1024;             // [8,16,1024,1024] fp32

    ushort_t* ws     = (ushort_t*)d_ws;
    ushort_t* q      = ws;                                   //  8M elts bf16 [B,H,N,64]
    ushort_t* kk     = ws + (size_t)8  * 1024 * 1024;        //  8M elts bf16 [B,H,N,64]
    ushort_t* vt     = ws + (size_t)16 * 1024 * 1024;        //  8M elts bf16 [B,H,64,N]
    ushort_t* ctx    = ws + (size_t)24 * 1024 * 1024;        //  8M elts bf16 [B,N,C]
    ushort_t* wqkvt  = ws + (size_t)32 * 1024 * 1024;        //  3M elts bf16 [3072,1024]
    ushort_t* wprojt = ws + (size_t)35 * 1024 * 1024;        //  1M elts bf16 [1024,1024]

    transpose_f32_bf16<<<dim3(96, 32), dim3(32, 8), 0, stream>>>(w_qkv, wqkvt, 1024, 3072);
    transpose_f32_bf16<<<dim3(32, 32), dim3(32, 8), 0, stream>>>(w_proj, wprojt, 1024, 1024);

    // QKV: [8192,1024] @ [1024,3072], A fp32
    gemm_bt<0, 1><<<dim3(24, 64), dim3(256), 0, stream>>>(x, wqkvt, 8192, 3072, 1024, q, (const float*)nullptr);

    // attention: 128 (b,h) * 64 q-tiles
    attn_fused<<<dim3(8192), dim3(256), 0, stream>>>(q, kk, vt, attn, ctx);

    // proj: [8192,1024] @ [1024,1024] + bias, A bf16, out fp32
    gemm_bt<1, 0><<<dim3(8, 64), dim3(256), 0, stream>>>(ctx, wprojt, 8192, 1024, 1024, out, b_proj);
}